// Round 8
// baseline (226.732 us; speedup 1.0000x reference)
//
#include <hip/hip_runtime.h>
#include <hip/hip_bf16.h>
#include <hip/hip_cooperative_groups.h>
#include <math.h>

namespace cg = cooperative_groups;

#define EPSF 1e-8f
// dims: B=32, C=384, H=W=32, L=1024, RF=24, RA=48

__device__ __forceinline__ float gelu_exact(float z) {
    return 0.5f * z * (1.0f + erff(z * 0.70710678118654752440f));
}
__device__ __forceinline__ float sigmoidf(float z) {
    return 1.0f / (1.0f + expf(-z));
}

// bf16 pack/unpack (no cvt_pk builtin on gfx950 -> inline asm)
__device__ __forceinline__ unsigned pk_bf16(float lo, float hi) {
    unsigned r;
    asm("v_cvt_pk_bf16_f32 %0, %1, %2" : "=v"(r) : "v"(lo), "v"(hi));
    return r;
}
__device__ __forceinline__ float ubf_lo(unsigned u) { return __uint_as_float(u << 16); }
__device__ __forceinline__ float ubf_hi(unsigned u) { return __uint_as_float(u & 0xFFFF0000u); }

// ---------- compile-time twiddles: cos/sin(2*pi*k/32) ----------
constexpr float cqv(int i) {
    return i == 0 ? 1.0f : i == 1 ? 0.980785280403230449f : i == 2 ? 0.923879532511286756f
         : i == 3 ? 0.831469612302545237f : i == 4 ? 0.707106781186547524f
         : i == 5 ? 0.555570233019602225f : i == 6 ? 0.382683432365089772f
         : i == 7 ? 0.195090322016128268f : 0.0f;  // i==8 -> 0
}
constexpr float c32f(int k) {
    k = ((k % 32) + 32) % 32;
    int kk = (k > 16) ? 32 - k : k;
    return (kk <= 8) ? cqv(kk) : -cqv(16 - kk);
}
constexpr float s32f(int k) { return c32f(k - 8); }

// ---------- stage 1: row DFT (along w), 1 row per lane ----------
template<int V, int W>
struct S1T {
    static __device__ __forceinline__ void run(const float (&r)[32], float& re, float& im) {
        constexpr float c = c32f(V * W);
        constexpr float s = s32f(V * W);
        if constexpr (c != 0.0f) re = fmaf(r[W], c, re);
        if constexpr (s != 0.0f) im = fmaf(r[W], -s, im);
        if constexpr (W + 1 < 32) S1T<V, W + 1>::run(r, re, im);
    }
};
template<int V>
struct S1V {
    static __device__ __forceinline__ void run(const float (&r)[32], unsigned* Rp, int base) {
        float re = 0.f, im = 0.f;
        S1T<V, 0>::run(r, re, im);
        Rp[base + V * 33] = pk_bf16(re, im);
        if constexpr (V + 1 < 17) S1V<V + 1>::run(r, Rp, base);
    }
};

// ---------- stage 2 kernel: complex dot with literal twiddles, N samples ----------
template<int U, int H, int HEND, int N>
struct S2T {
    static __device__ __forceinline__ void run(const float (&ar)[N], const float (&ai)[N],
                                               float& re, float& im) {
        constexpr float c = c32f(U * H);
        constexpr float s = s32f(U * H);
        if constexpr (c != 0.0f) { re = fmaf(ar[H], c, re); im = fmaf(ai[H], c, im); }
        if constexpr (s != 0.0f) { re = fmaf(ai[H], s, re); im = fmaf(ar[H], -s, im); }
        if constexpr (H + 1 < HEND) S2T<U, H + 1, HEND, N>::run(ar, ai, re, im);
    }
};

// high bins u in [8,32): 16-h half-partial, sign-fix odd u, pair combine, mag
template<int U>
struct HighU {
    static __device__ __forceinline__ void run(const float (&dr)[16], const float (&di)[16],
                                               float sgn, float& acc) {
        float re = 0.f, im = 0.f;
        S2T<U, 0, 16, 16>::run(dr, di, re, im);
        if constexpr (U & 1) { re *= sgn; im *= sgn; }
        float tr = re + __shfl_xor(re, 1);
        float ti = im + __shfl_xor(im, 1);
        acc += sqrtf(fmaf(tr, tr, ti * ti));
        if constexpr (U + 1 < 32) HighU<U + 1>::run(dr, di, sgn, acc);
    }
};

// low bins u in [0,8): 4-sample partial, rotate by w_k(u)=e^{-i pi u k/4}, 8-lane reduce, mag
template<int U>
struct LowU {
    static __device__ __forceinline__ void run(const float (&er)[4], const float (&ei)[4],
                                               float wre, float wim, float brc, float brs,
                                               float& acc) {
        float pr = 0.f, pi = 0.f;
        S2T<U, 0, 4, 4>::run(er, ei, pr, pi);
        float vr = pr * wre - pi * wim;
        float vi = pr * wim + pi * wre;
        vr += __shfl_xor(vr, 1); vi += __shfl_xor(vi, 1);
        vr += __shfl_xor(vr, 2); vi += __shfl_xor(vi, 2);
        vr += __shfl_xor(vr, 4); vi += __shfl_xor(vi, 4);
        acc += sqrtf(fmaf(vr, vr, vi * vi));
        if constexpr (U + 1 < 8) {
            float nre = fmaf(wre, brc, -wim * brs);
            float nim = fmaf(wre, brs, wim * brc);
            LowU<U + 1>::run(er, ei, nre, nim, brc, brs, acc);
        }
    }
};

// =======================================================================
// Cooperative mega-kernel: P1 energy -> P2 freq-MLP -> P3 LN+Spart ->
// P4 attn-MLP -> P5 transpose-scale output. grid.sync between phases.
// =======================================================================
__global__ void __launch_bounds__(256) mega(
    const float* __restrict__ x,
    const float* __restrict__ w1, const float* __restrict__ b1,
    const float* __restrict__ w2, const float* __restrict__ b2,
    const float* __restrict__ alp,
    const float* __restrict__ lng, const float* __restrict__ lnb,
    const float* __restrict__ wg, const float* __restrict__ bg,
    const float* __restrict__ wcp, const float* __restrict__ bcp,
    float* __restrict__ out, float* __restrict__ ws)
{
    cg::grid_group grid = cg::this_grid();
    __shared__ __align__(16) char sm[21504];
    float* energy = ws;              // 32*768
    float* gw     = ws + 24576;      // 32*384
    float* mu     = ws + 36864;      // 32*1024
    float* rr     = ws + 69632;      // 32*1024
    float* Spart  = ws + 102400;     // 32*32*384
    float* ga     = ws + 495616;     // 32*384
    const int t = threadIdx.x;

    // ---------------- P1: rfft2 magnitudes -> energy ----------------
    {
        unsigned* Rp = (unsigned*)sm;          // 8*561 words = 17952 B
        const int pair = t >> 5, h = t & 31, q = t & 31;
        for (int vb = blockIdx.x; vb < 1536; vb += gridDim.x) {
            const int bc0 = vb * 8;
            const float4* src = (const float4*)(x + (size_t)(bc0 + pair) * 1024 + h * 32);
            float r[32];
#pragma unroll
            for (int k = 0; k < 8; ++k) {
                float4 a = src[k];
                r[4*k+0] = a.x + EPSF; r[4*k+1] = a.y + EPSF;
                r[4*k+2] = a.z + EPSF; r[4*k+3] = a.w + EPSF;
            }
            S1V<0>::run(r, Rp, pair * 561 + h);
            __syncthreads();
            // high: 13 cols (v=4..16) x 2 h-halves = 26 tasks/img
            float acch = 0.f;
            {
                const int vq = (q < 26) ? (4 + (q >> 1)) : 4;
                const int h0 = (q < 26) ? ((q & 1) << 4) : 0;
                const unsigned* bp = &Rp[pair * 561 + vq * 33 + h0];
                float dr[16], di[16];
#pragma unroll
                for (int k = 0; k < 16; ++k) { unsigned u = bp[k]; dr[k] = ubf_lo(u); di[k] = ubf_hi(u); }
                const float sgn = (h0 != 0) ? -1.0f : 1.0f;
                HighU<8>::run(dr, di, sgn, acch);
            }
            // low: 4 cols x 8 h-eighths = 32 tasks/img
            float accl = 0.f;
            {
                const int v2 = q >> 3, k8 = q & 7;
                const unsigned* lp = &Rp[pair * 561 + v2 * 33 + k8 * 4];
                float er[4], ei[4];
#pragma unroll
                for (int j = 0; j < 4; ++j) { unsigned u = lp[j]; er[j] = ubf_lo(u); ei[j] = ubf_hi(u); }
                float sb, cb;
                sincosf(0.78539816339744831f * (float)k8, &sb, &cb);
                LowU<0>::run(er, ei, 1.0f, 0.0f, cb, -sb, accl);
            }
            float hv = (q < 26) ? acch : 0.f;
#pragma unroll
            for (int off = 1; off <= 16; off <<= 1) {
                hv   += __shfl_xor(hv, off);
                accl += __shfl_xor(accl, off);
            }
            if (q == 0) {
                const int bc = bc0 + pair;
                const int b = bc / 384, c = bc - 384 * b;
                energy[b * 768 + c]       = accl * (1.0f / 8192.0f)  + EPSF;
                energy[b * 768 + 384 + c] = hv   * (1.0f / 19968.0f) + EPSF;
            }
            __syncthreads();   // protect Rp before next iteration's writes
        }
    }
    grid.sync();

    // ---------------- P2: gw = 1 + alpha*sigmoid(MLP(energy)) ----------------
    {
        float* e   = (float*)sm;     // 768
        float* hid = e + 768;        // 24
        for (int b = blockIdx.x; b < 32; b += gridDim.x) {
            for (int i = t; i < 768; i += 256) e[i] = energy[b * 768 + i];
            __syncthreads();
            if (t < 24) {
                float a0 = 0.f, a1 = 0.f, a2 = 0.f, a3 = 0.f;
                for (int k = 0; k < 768; k += 4) {
                    a0 = fmaf(e[k+0], w1[(k+0) * 24 + t], a0);
                    a1 = fmaf(e[k+1], w1[(k+1) * 24 + t], a1);
                    a2 = fmaf(e[k+2], w1[(k+2) * 24 + t], a2);
                    a3 = fmaf(e[k+3], w1[(k+3) * 24 + t], a3);
                }
                hid[t] = gelu_exact(((a0 + a1) + (a2 + a3)) + b1[t]);
            }
            __syncthreads();
            const float alpha = alp[0];
            for (int c = t; c < 384; c += 256) {
                float z = b2[c];
#pragma unroll
                for (int j = 0; j < 24; ++j) z = fmaf(hid[j], w2[j * 384 + c], z);
                gw[b * 384 + c] = fmaf(alpha, sigmoidf(z), 1.0f);
            }
            __syncthreads();
        }
    }
    grid.sync();

    // ---------------- P3: LN stats (mu, rr) + Spart, float4 loads ----------------
    {
        float (*ls)[33]   = (float(*)[33])sm;             // 32*33*4 = 4224
        float (*lq)[33]   = (float(*)[33])(sm + 4224);    // 4224
        float* r_sh       = (float*)(sm + 8448);          // 128
        float (*spB)[385] = (float(*)[385])(sm + 8576);   // 8*385*4 = 12320 -> 20896 total
        const int cq = t >> 3, l4 = t & 7;
        for (int vb = blockIdx.x; vb < 1024; vb += gridDim.x) {
            const int b = vb >> 5, sl = vb & 31;
            const float* xb = x + (size_t)b * 393216 + sl * 32;
            const float* wb = gw + b * 384;
            // phase A: thread (cq,l4) covers c in [cq*12, cq*12+12), l-quad l4
            {
                float s0=0.f,s1=0.f,s2=0.f,s3=0.f,q0=0.f,q1=0.f,q2=0.f,q3=0.f;
#pragma unroll
                for (int k = 0; k < 12; ++k) {
                    const int c = cq * 12 + k;
                    float4 v = *(const float4*)(xb + (size_t)c * 1024 + l4 * 4);
                    const float w = wb[c];
                    float f0 = w * v.x, f1 = w * v.y, f2 = w * v.z, f3 = w * v.w;
                    s0 += f0; s1 += f1; s2 += f2; s3 += f3;
                    q0 = fmaf(f0, f0, q0); q1 = fmaf(f1, f1, q1);
                    q2 = fmaf(f2, f2, q2); q3 = fmaf(f3, f3, q3);
                }
                ls[cq][l4*4+0] = s0; ls[cq][l4*4+1] = s1; ls[cq][l4*4+2] = s2; ls[cq][l4*4+3] = s3;
                lq[cq][l4*4+0] = q0; lq[cq][l4*4+1] = q1; lq[cq][l4*4+2] = q2; lq[cq][l4*4+3] = q3;
            }
            __syncthreads();
            if (t < 32) {
                float S = 0.f, Q = 0.f;
#pragma unroll
                for (int i = 0; i < 32; ++i) { S += ls[i][t]; Q += lq[i][t]; }
                float m = S * (1.0f / 384.0f);
                float var = Q * (1.0f / 384.0f) - m * m;
                float rv = rsqrtf(var + 1e-5f);
                mu[b * 1024 + sl * 32 + t] = m;
                rr[b * 1024 + sl * 32 + t] = rv;
                r_sh[t] = rv;
            }
            __syncthreads();
            // phase B: reload (L1-hot) and dot with r; reduce over l-quads via LDS
            {
                const float rv0 = r_sh[l4*4+0], rv1 = r_sh[l4*4+1];
                const float rv2 = r_sh[l4*4+2], rv3 = r_sh[l4*4+3];
#pragma unroll
                for (int k = 0; k < 12; ++k) {
                    const int c = cq * 12 + k;
                    float4 v = *(const float4*)(xb + (size_t)c * 1024 + l4 * 4);
                    float p = v.x * rv0;
                    p = fmaf(v.y, rv1, p);
                    p = fmaf(v.z, rv2, p);
                    p = fmaf(v.w, rv3, p);
                    spB[l4][c] = p;
                }
            }
            __syncthreads();
            for (int c = t; c < 384; c += 256) {
                float a = 0.f;
#pragma unroll
                for (int i = 0; i < 8; ++i) a += spB[i][c];
                Spart[((size_t)b * 32 + sl) * 384 + c] = a;
            }
            __syncthreads();
        }
    }
    grid.sync();

    // ---------------- P4: ga = 4*sigmoid(MLP(xg))*gw ----------------
    {
        float* xg  = (float*)sm;     // 384
        float* hid = xg + 384;       // 48
        float* red = hid + 48;       // 4
        for (int b = blockIdx.x; b < 32; b += gridDim.x) {
            float p = 0.f;
            for (int l = t; l < 1024; l += 256) p += mu[b * 1024 + l] * rr[b * 1024 + l];
#pragma unroll
            for (int off = 32; off > 0; off >>= 1) p += __shfl_down(p, off, 64);
            if ((t & 63) == 0) red[t >> 6] = p;
            __syncthreads();
            const float T = red[0] + red[1] + red[2] + red[3];
            for (int c = t; c < 384; c += 256) {
                float Sraw = 0.f;
                const float* sp = Spart + (size_t)b * 12288 + c;
#pragma unroll 8
                for (int sl = 0; sl < 32; ++sl) Sraw += sp[sl * 384];
                float Sc = gw[b * 384 + c] * Sraw;
                xg[c] = fmaf(lng[c], (Sc - T) * (1.0f / 1024.0f), 0.0f) + lnb[c];
            }
            __syncthreads();
            if (t < 48) {
                float a0 = 0.f, a1 = 0.f, a2 = 0.f, a3 = 0.f;
                for (int k = 0; k < 384; k += 4) {
                    a0 = fmaf(xg[k+0], wg[(k+0) * 48 + t], a0);
                    a1 = fmaf(xg[k+1], wg[(k+1) * 48 + t], a1);
                    a2 = fmaf(xg[k+2], wg[(k+2) * 48 + t], a2);
                    a3 = fmaf(xg[k+3], wg[(k+3) * 48 + t], a3);
                }
                hid[t] = gelu_exact(((a0 + a1) + (a2 + a3)) + bg[t]);
            }
            __syncthreads();
            for (int c = t; c < 384; c += 256) {
                float z = bcp[c];
#pragma unroll
                for (int j = 0; j < 48; ++j) z = fmaf(hid[j], wcp[j * 384 + c], z);
                ga[b * 384 + c] = 4.0f * sigmoidf(z) * gw[b * 384 + c];
            }
            __syncthreads();
        }
    }
    grid.sync();

    // ---------------- P5: out[b,l,c] = x[b,c,l]*ga[b,c], float4 both sides ----------------
    {
        float (*tile)[65] = (float(*)[65])sm;   // 64*65*4 = 16640
        const int ccl = t >> 4, l4 = t & 15;    // load indexing
        const int c4 = (t & 15) * 4, lb = t >> 4;  // store indexing
        for (int vb = blockIdx.x; vb < 3072; vb += gridDim.x) {
            const int b = vb / 96, rem = vb - 96 * b;
            const int lt = rem / 6, ct = rem - 6 * lt;
            const float* xb = x + ((size_t)b * 384 + ct * 64) * 1024 + lt * 64;
#pragma unroll
            for (int i = 0; i < 4; ++i) {
                const int row = i * 16 + ccl;
                const float coeff = ga[b * 384 + ct * 64 + row];
                float4 v = *(const float4*)(xb + (size_t)row * 1024 + l4 * 4);
                tile[row][l4*4+0] = coeff * v.x;
                tile[row][l4*4+1] = coeff * v.y;
                tile[row][l4*4+2] = coeff * v.z;
                tile[row][l4*4+3] = coeff * v.w;
            }
            __syncthreads();
            float* ob = out + ((size_t)b * 1024 + lt * 64) * 384 + ct * 64;
#pragma unroll
            for (int rep = 0; rep < 4; ++rep) {
                const int ll = rep * 16 + lb;
                float4 v;
                v.x = tile[c4 + 0][ll];
                v.y = tile[c4 + 1][ll];
                v.z = tile[c4 + 2][ll];
                v.w = tile[c4 + 3][ll];
                *(float4*)(ob + (size_t)ll * 384 + c4) = v;
            }
            __syncthreads();
        }
    }
}

extern "C" void kernel_launch(void* const* d_in, const int* in_sizes, int n_in,
                              void* d_out, int out_size, void* d_ws, size_t ws_size,
                              hipStream_t stream) {
    const float* x   = (const float*)d_in[0];
    const float* w1  = (const float*)d_in[1];
    const float* b1  = (const float*)d_in[2];
    const float* w2  = (const float*)d_in[3];
    const float* b2  = (const float*)d_in[4];
    const float* alp = (const float*)d_in[5];
    const float* lng = (const float*)d_in[6];
    const float* lnb = (const float*)d_in[7];
    const float* wg  = (const float*)d_in[8];
    const float* bg  = (const float*)d_in[9];
    const float* wcp = (const float*)d_in[10];
    const float* bcp = (const float*)d_in[11];
    float* out = (float*)d_out;
    float* ws  = (float*)d_ws;

    void* args[14] = {
        (void*)&x, (void*)&w1, (void*)&b1, (void*)&w2, (void*)&b2, (void*)&alp,
        (void*)&lng, (void*)&lnb, (void*)&wg, (void*)&bg, (void*)&wcp, (void*)&bcp,
        (void*)&out, (void*)&ws
    };
    int nb = 0;
    hipError_t err = hipOccupancyMaxActiveBlocksPerMultiprocessor(&nb, (const void*)mega, 256, 0);
    if (err != hipSuccess || nb < 1) nb = 1;
    long long grid = (long long)nb * 256;   // 256 CUs on MI355X
    if (grid > 1024) grid = 1024;           // >= P3's natural width; phases grid-stride anyway
    hipLaunchCooperativeKernel((const void*)mega, dim3((unsigned)grid), dim3(256),
                               args, 0, stream);
}

// Round 10
// 97.636 us; speedup vs baseline: 2.3222x; 2.3222x over previous
//
#include <hip/hip_runtime.h>
#include <hip/hip_bf16.h>
#include <math.h>

#define EPSF 1e-8f
// dims: B=32, C=384, H=W=32, L=1024, RF=24, RA=48

__device__ __forceinline__ float gelu_exact(float z) {
    return 0.5f * z * (1.0f + erff(z * 0.70710678118654752440f));
}
__device__ __forceinline__ float sigmoidf(float z) {
    return 1.0f / (1.0f + expf(-z));
}

// bf16 pack/unpack (no cvt_pk builtin on gfx950 -> inline asm)
__device__ __forceinline__ unsigned pk_bf16(float lo, float hi) {
    unsigned r;
    asm("v_cvt_pk_bf16_f32 %0, %1, %2" : "=v"(r) : "v"(lo), "v"(hi));
    return r;
}
__device__ __forceinline__ float ubf_lo(unsigned u) { return __uint_as_float(u << 16); }
__device__ __forceinline__ float ubf_hi(unsigned u) { return __uint_as_float(u & 0xFFFF0000u); }

// ---------- compile-time twiddles: cos/sin(2*pi*k/32) ----------
constexpr float cqv(int i) {
    return i == 0 ? 1.0f : i == 1 ? 0.980785280403230449f : i == 2 ? 0.923879532511286756f
         : i == 3 ? 0.831469612302545237f : i == 4 ? 0.707106781186547524f
         : i == 5 ? 0.555570233019602225f : i == 6 ? 0.382683432365089772f
         : i == 7 ? 0.195090322016128268f : 0.0f;  // i==8 -> 0
}
constexpr float c32f(int k) {
    k = ((k % 32) + 32) % 32;
    int kk = (k > 16) ? 32 - k : k;
    return (kk <= 8) ? cqv(kk) : -cqv(16 - kk);
}
constexpr float s32f(int k) { return c32f(k - 8); }

// acc += w32^TI * (br + i*bi), optionally conjugating (br,bi). All literal.
template<int TI, bool CJ>
__device__ __forceinline__ void cmadd(float br, float bi, float& re, float& im) {
    constexpr float c0 = c32f(TI), s0 = s32f(TI);
    constexpr float sE = CJ ? -s0 : s0;
    constexpr float cE = CJ ? -c0 : c0;
    if constexpr (c0 != 0.f) re = fmaf(br, c0, re);
    if constexpr (s0 != 0.f) re = fmaf(bi, sE, re);
    if constexpr (c0 != 0.f) im = fmaf(bi, cE, im);
    if constexpr (s0 != 0.f) im = fmaf(br, -s0, im);
}

// ---------- stage 1: real 8-sample sub-DFTs (k mod 4 residues), base w8=w32^4 ----------
template<int RR, int N, int P>
struct G8 {
    static __device__ __forceinline__ void run(const float (&r)[32], float& re, float& im) {
        constexpr int ti = (4 * N * P) % 32;
        constexpr float c = c32f(ti), s = s32f(ti);
        if constexpr (c != 0.f) re = fmaf(r[4*P+RR], c, re);
        if constexpr (s != 0.f) im = fmaf(r[4*P+RR], -s, im);
        if constexpr (P + 1 < 8) G8<RR, N, P+1>::run(r, re, im);
    }
};
template<int RR, int N>
struct G8N {
    static __device__ __forceinline__ void run(const float (&r)[32], float (&Gre)[4][5], float (&Gim)[4][5]) {
        float re = 0.f, im = 0.f;
        G8<RR, N, 0>::run(r, re, im);
        Gre[RR][N] = re; Gim[RR][N] = im;
        if constexpr (N + 1 < 5) G8N<RR, N+1>::run(r, Gre, Gim);
    }
};
template<int RR>
struct G8R {
    static __device__ __forceinline__ void run(const float (&r)[32], float (&Gre)[4][5], float (&Gim)[4][5]) {
        G8N<RR, 0>::run(r, Gre, Gim);
        if constexpr (RR + 1 < 4) G8R<RR+1>::run(r, Gre, Gim);
    }
};
// stage-1 combine: R[v] = sum_r w32^{v r} G_r[v mod 8], conj-fetch for n>4 (real symmetry)
template<int V>
struct S1C {
    static __device__ __forceinline__ void run(const float (&Gre)[4][5], const float (&Gim)[4][5],
                                               unsigned* Rp, int base) {
        constexpr int n = V & 7;
        constexpr int nn = (n <= 4) ? n : 8 - n;
        constexpr bool cj = (n > 4);
        float re = 0.f, im = 0.f;
        cmadd<0,   cj>(Gre[0][nn], Gim[0][nn], re, im);
        cmadd<V,   cj>(Gre[1][nn], Gim[1][nn], re, im);
        cmadd<2*V, cj>(Gre[2][nn], Gim[2][nn], re, im);
        cmadd<3*V, cj>(Gre[3][nn], Gim[3][nn], re, im);
        Rp[base + V * 33] = pk_bf16(re, im);
        if constexpr (V + 1 < 17) S1C<V+1>::run(Gre, Gim, Rp, base);
    }
};

// ---------- stage 2 high: complex 4-sample sub-DFTs (k mod 4), base w8 ----------
template<int RR, int N, int P>
struct D4 {
    static __device__ __forceinline__ void run(const float (&dr)[16], const float (&di)[16],
                                               float& re, float& im) {
        cmadd<(4*N*P) % 32, false>(dr[4*P+RR], di[4*P+RR], re, im);
        if constexpr (P + 1 < 4) D4<RR, N, P+1>::run(dr, di, re, im);
    }
};
template<int RR, int N>
struct D4N {
    static __device__ __forceinline__ void run(const float (&dr)[16], const float (&di)[16],
                                               float (&Dre)[4][8], float (&Dim)[4][8]) {
        float re = 0.f, im = 0.f;
        D4<RR, N, 0>::run(dr, di, re, im);
        Dre[RR][N] = re; Dim[RR][N] = im;
        if constexpr (N + 1 < 8) D4N<RR, N+1>::run(dr, di, Dre, Dim);
    }
};
template<int RR>
struct D4R {
    static __device__ __forceinline__ void run(const float (&dr)[16], const float (&di)[16],
                                               float (&Dre)[4][8], float (&Dim)[4][8]) {
        D4N<RR, 0>::run(dr, di, Dre, Dim);
        if constexpr (RR + 1 < 4) D4R<RR+1>::run(dr, di, Dre, Dim);
    }
};
// stage-2 combine+mag: P[u] = sum_r w32^{u r} D_r[u mod 8]; half-split sign fix + pair shfl
template<int U>
struct S2C {
    static __device__ __forceinline__ void run(const float (&Dre)[4][8], const float (&Dim)[4][8],
                                               float sgn, float& acc) {
        constexpr int n = U & 7;
        float re = 0.f, im = 0.f;
        cmadd<0,   false>(Dre[0][n], Dim[0][n], re, im);
        cmadd<U,   false>(Dre[1][n], Dim[1][n], re, im);
        cmadd<2*U, false>(Dre[2][n], Dim[2][n], re, im);
        cmadd<3*U, false>(Dre[3][n], Dim[3][n], re, im);
        if constexpr (U & 1) { re *= sgn; im *= sgn; }
        float tr = re + __shfl_xor(re, 1);
        float ti = im + __shfl_xor(im, 1);
        acc += sqrtf(fmaf(tr, tr, ti * ti));
        if constexpr (U + 1 < 32) S2C<U+1>::run(Dre, Dim, sgn, acc);
    }
};

// ---------- low bins: 4-sample partial + runtime rotation + 8-lane reduce ----------
template<int U, int H, int HEND, int N>
struct S2T {
    static __device__ __forceinline__ void run(const float (&ar)[N], const float (&ai)[N],
                                               float& re, float& im) {
        constexpr float c = c32f(U * H);
        constexpr float s = s32f(U * H);
        if constexpr (c != 0.0f) { re = fmaf(ar[H], c, re); im = fmaf(ai[H], c, im); }
        if constexpr (s != 0.0f) { re = fmaf(ai[H], s, re); im = fmaf(ar[H], -s, im); }
        if constexpr (H + 1 < HEND) S2T<U, H + 1, HEND, N>::run(ar, ai, re, im);
    }
};
template<int U>
struct LowU {
    static __device__ __forceinline__ void run(const float (&er)[4], const float (&ei)[4],
                                               float wre, float wim, float brc, float brs,
                                               float& acc) {
        float pr = 0.f, pi = 0.f;
        S2T<U, 0, 4, 4>::run(er, ei, pr, pi);
        float vr = pr * wre - pi * wim;
        float vi = pr * wim + pi * wre;
        vr += __shfl_xor(vr, 1); vi += __shfl_xor(vi, 1);
        vr += __shfl_xor(vr, 2); vi += __shfl_xor(vi, 2);
        vr += __shfl_xor(vr, 4); vi += __shfl_xor(vi, 4);
        acc += sqrtf(fmaf(vr, vr, vi * vi));
        if constexpr (U + 1 < 8) {
            float nre = fmaf(wre, brc, -wim * brs);
            float nim = fmaf(wre, brs, wim * brc);
            LowU<U + 1>::run(er, ei, nre, nim, brc, brs, acc);
        }
    }
};

// ---------------- K1: per-image rfft2 magnitudes -> energy[b, 2C] ----------------
// 2 images/wave, grid 6144. Radix-4 two-level DFT, literal twiddles throughout.
__global__ void __launch_bounds__(64) k1_energy(const float* __restrict__ x,
                                                float* __restrict__ energy) {
    __shared__ __align__(16) unsigned Rp[2 * 561];
    const int t = threadIdx.x;
    const int img = t >> 5, h = t & 31;
    const int bc0 = blockIdx.x * 2;
    const float4* src = (const float4*)(x + (size_t)(bc0 + img) * 1024 + h * 32);
    float r[32];
#pragma unroll
    for (int k = 0; k < 8; ++k) {
        float4 a = src[k];
        r[4*k+0] = a.x; r[4*k+1] = a.y; r[4*k+2] = a.z; r[4*k+3] = a.w;
        // (+EPSF dropped: only shifts bin(0,0) by ~3e-7 -> out by <1e-9)
    }
    {
        float Gre[4][5], Gim[4][5];
        G8R<0>::run(r, Gre, Gim);
        S1C<0>::run(Gre, Gim, Rp, img * 561 + h);
    }
    __syncthreads();

    const int q = t & 31;
    // ---- high phase: 13 columns (v=4..16) x 2 h-halves = 26 tasks/img ----
    float acch = 0.f;
    {
        const int vq = (q < 26) ? (4 + (q >> 1)) : 4;
        const int h0 = (q < 26) ? ((q & 1) << 4) : 0;
        const unsigned* bp = &Rp[img * 561 + vq * 33 + h0];
        float dr[16], di[16];
#pragma unroll
        for (int k = 0; k < 16; ++k) { unsigned u = bp[k]; dr[k] = ubf_lo(u); di[k] = ubf_hi(u); }
        const float sgn = (h0 != 0) ? -1.0f : 1.0f;
        float Dre[4][8], Dim[4][8];
        D4R<0>::run(dr, di, Dre, Dim);
        S2C<8>::run(Dre, Dim, sgn, acch);
    }
    // ---- low phase: 4 columns (v=0..3) x 8 h-eighths = 32 tasks/img ----
    float accl = 0.f;
    {
        const int v2 = q >> 3, k8 = q & 7;
        const unsigned* lp = &Rp[img * 561 + v2 * 33 + k8 * 4];
        float er[4], ei[4];
#pragma unroll
        for (int j = 0; j < 4; ++j) { unsigned u = lp[j]; er[j] = ubf_lo(u); ei[j] = ubf_hi(u); }
        float sb, cb;
        sincosf(0.78539816339744831f * (float)k8, &sb, &cb);
        LowU<0>::run(er, ei, 1.0f, 0.0f, cb, -sb, accl);
    }
    float hv = (q < 26) ? acch : 0.f;
#pragma unroll
    for (int off = 1; off <= 16; off <<= 1) {
        hv   += __shfl_xor(hv, off);
        accl += __shfl_xor(accl, off);
    }
    if (q == 0) {
        const int bc = bc0 + img;
        const int b = bc / 384, c = bc - 384 * b;
        energy[b * 768 + c]       = accl * (1.0f / 8192.0f)  + EPSF;  // /(8 dup * 32 bins * 32 norm)
        energy[b * 768 + 384 + c] = hv   * (1.0f / 19968.0f) + EPSF;  // /(2 dup * 312 bins * 32 norm)
    }
}

// ---------------- K34: gw (fused k2) + LN stats + partial S ----------------
// Block = (b, l-slice of 32), 384 threads. Phase 0 recomputes gw[b,:] per block
// (energy+w1 are L2-hot; ~150 ops/thread) -- deletes the separate k2 launch.
// R9 crash fix: phase A is 12 groups x 32 c's (c = g8*32+cc, max 383), NOT 48.
__global__ void __launch_bounds__(384) k34_stats_S(const float* __restrict__ x,
                                                   const float* __restrict__ energy,
                                                   const float* __restrict__ w1,
                                                   const float* __restrict__ b1,
                                                   const float* __restrict__ w2,
                                                   const float* __restrict__ b2,
                                                   const float* __restrict__ alp,
                                                   float* __restrict__ gw,
                                                   float* __restrict__ mu,
                                                   float* __restrict__ rr,
                                                   float* __restrict__ Spart) {
    const int b = blockIdx.x >> 5, sl = blockIdx.x & 31;
    const int t = threadIdx.x;
    __shared__ float e[768];
    __shared__ float hid24[24];
    __shared__ float gw_sh[384];
    __shared__ float ls[12][32], lq[12][32];
    __shared__ float r_sh[32];
    // ---- phase 0: gw = 1 + alpha*sigmoid(MLP(energy)) ----
    e[t] = energy[b * 768 + t];
    e[t + 384] = energy[b * 768 + 384 + t];
    __syncthreads();
    {
        const int j = t >> 4, s = t & 15;   // 24 hidden x 16 slices of 48
        const int k0 = s * 48;
        float a0 = 0.f, a1 = 0.f;
#pragma unroll
        for (int k = 0; k < 48; k += 2) {
            a0 = fmaf(e[k0 + k],     w1[(k0 + k) * 24 + j],     a0);
            a1 = fmaf(e[k0 + k + 1], w1[(k0 + k + 1) * 24 + j], a1);
        }
        float a = a0 + a1;
        a += __shfl_xor(a, 1); a += __shfl_xor(a, 2);
        a += __shfl_xor(a, 4); a += __shfl_xor(a, 8);
        if (s == 0) hid24[j] = gelu_exact(a + b1[j]);
    }
    __syncthreads();
    {
        float z = b2[t];
#pragma unroll
        for (int j = 0; j < 24; ++j) z = fmaf(hid24[j], w2[j * 384 + t], z);
        float g = fmaf(alp[0], sigmoidf(z), 1.0f);
        gw_sh[t] = g;
        if (sl == 0) gw[b * 384 + t] = g;    // publish for k5
    }
    __syncthreads();
    // ---- phase A: LN stats over C for 32 l's (12 groups x 32 c's) ----
    const float* xb = x + (size_t)b * 393216 + sl * 32;
    const int g8 = t >> 5, l5 = t & 31;
    {
        float s = 0.0f, qa = 0.0f;
#pragma unroll 8
        for (int cc = 0; cc < 32; ++cc) {
            const int c = g8 * 32 + cc;
            float xf = gw_sh[c] * xb[(size_t)c * 1024 + l5];
            s += xf;
            qa = fmaf(xf, xf, qa);
        }
        ls[g8][l5] = s;
        lq[g8][l5] = qa;
    }
    __syncthreads();
    if (t < 32) {
        float S = 0.f, Q = 0.f;
#pragma unroll
        for (int i = 0; i < 12; ++i) { S += ls[i][t]; Q += lq[i][t]; }
        float m = S * (1.0f / 384.0f);
        float var = Q * (1.0f / 384.0f) - m * m;
        float rv = rsqrtf(var + 1e-5f);
        mu[b * 1024 + sl * 32 + t] = m;
        rr[b * 1024 + sl * 32 + t] = rv;
        r_sh[t] = rv;
    }
    __syncthreads();
    // ---- phase B: Spart[b,sl,c] = sum_{l in slice} x*r (L2-hot re-read) ----
    {
        const float4* xc = (const float4*)(xb + (size_t)t * 1024);
        float acc = 0.f;
#pragma unroll
        for (int k = 0; k < 8; ++k) {
            float4 v = xc[k];
            acc = fmaf(v.x, r_sh[4*k+0], acc);
            acc = fmaf(v.y, r_sh[4*k+1], acc);
            acc = fmaf(v.z, r_sh[4*k+2], acc);
            acc = fmaf(v.w, r_sh[4*k+3], acc);
        }
        Spart[((size_t)b * 32 + sl) * 384 + t] = acc;   // raw (gw applied in k5)
    }
}

// ---------------- K5: ga[b,c] = 4*sigmoid(gelu(xg@wg+bg)@wc+bc) * gw, per b ----------------
__global__ void __launch_bounds__(384) k5_attn(const float* __restrict__ Spart,
                                               const float* __restrict__ mu,
                                               const float* __restrict__ rr,
                                               const float* __restrict__ g,
                                               const float* __restrict__ beta,
                                               const float* __restrict__ wg,
                                               const float* __restrict__ bg,
                                               const float* __restrict__ wc,
                                               const float* __restrict__ bc_,
                                               const float* __restrict__ gw,
                                               float* __restrict__ ga) {
    __shared__ float red[6];
    __shared__ float xg[384];
    __shared__ float hid[48];
    const int b = blockIdx.x, t = threadIdx.x;
    const int wv = t >> 6, lane = t & 63;
    float p = 0.0f;
    for (int l = t; l < 1024; l += 384) p += mu[b * 1024 + l] * rr[b * 1024 + l];
#pragma unroll
    for (int off = 32; off > 0; off >>= 1) p += __shfl_down(p, off, 64);
    if (lane == 0) red[wv] = p;
    float Sraw = 0.f;
    {
        const float* sp = Spart + (size_t)b * 12288 + t;
#pragma unroll 8
        for (int sl = 0; sl < 32; ++sl) Sraw += sp[sl * 384];
    }
    __syncthreads();
    float T = red[0] + red[1] + red[2] + red[3] + red[4] + red[5];
    float Sc = gw[b * 384 + t] * Sraw;
    xg[t] = fmaf(g[t], (Sc - T) * (1.0f / 1024.0f), 0.0f) + beta[t];
    __syncthreads();
    {
        const int j = t >> 3, s = t & 7;    // 48 hidden x 8 slices of 48
        float a0 = 0.f, a1 = 0.f;
        const int k0 = s * 48;
#pragma unroll
        for (int k = 0; k < 48; k += 2) {
            a0 = fmaf(xg[k0 + k],     wg[(k0 + k) * 48 + j],     a0);
            a1 = fmaf(xg[k0 + k + 1], wg[(k0 + k + 1) * 48 + j], a1);
        }
        float a = a0 + a1;
        a += __shfl_xor(a, 1); a += __shfl_xor(a, 2); a += __shfl_xor(a, 4);
        if (s == 0) hid[j] = gelu_exact(a + bg[j]);
    }
    __syncthreads();
    float z = bc_[t];
#pragma unroll
    for (int j = 0; j < 48; ++j) z = fmaf(hid[j], wc[j * 384 + t], z);
    ga[b * 384 + t] = 4.0f * sigmoidf(z) * gw[b * 384 + t];
}

// ---------------- K6: out[b,l,c] = x[b,c,l] * ga[b,c] (LDS transpose, float4 stores) ----------
__global__ void __launch_bounds__(256) k6_out(const float* __restrict__ x,
                                              const float* __restrict__ ga,
                                              float* __restrict__ out) {
    __shared__ float tile[64][65];
    const int id = blockIdx.x;
    const int b = id / 96, rem = id - 96 * b;
    const int lt = rem / 6, ct = rem - 6 * lt;
    const int t = threadIdx.x, w = t >> 6, lane = t & 63;
    const float* xb = x + ((size_t)b * 384 + ct * 64) * 1024 + lt * 64;
#pragma unroll
    for (int i = 0; i < 16; ++i) {
        int cc = w + 4 * i;
        float coeff = ga[b * 384 + ct * 64 + cc];
        tile[cc][lane] = coeff * xb[(size_t)cc * 1024 + lane];
    }
    __syncthreads();
    const int c4 = (t & 15) * 4;
    const int lb = t >> 4;
    float* ob = out + ((size_t)b * 1024 + lt * 64) * 384 + ct * 64;
#pragma unroll
    for (int rep = 0; rep < 4; ++rep) {
        int ll = rep * 16 + lb;
        float4 v;
        v.x = tile[c4 + 0][ll];
        v.y = tile[c4 + 1][ll];
        v.z = tile[c4 + 2][ll];
        v.w = tile[c4 + 3][ll];
        *(float4*)(ob + (size_t)ll * 384 + c4) = v;
    }
}

extern "C" void kernel_launch(void* const* d_in, const int* in_sizes, int n_in,
                              void* d_out, int out_size, void* d_ws, size_t ws_size,
                              hipStream_t stream) {
    const float* x   = (const float*)d_in[0];
    const float* w1  = (const float*)d_in[1];
    const float* b1  = (const float*)d_in[2];
    const float* w2  = (const float*)d_in[3];
    const float* b2  = (const float*)d_in[4];
    const float* alp = (const float*)d_in[5];
    const float* lng = (const float*)d_in[6];
    const float* lnb = (const float*)d_in[7];
    const float* wg  = (const float*)d_in[8];
    const float* bg  = (const float*)d_in[9];
    const float* wc  = (const float*)d_in[10];
    const float* bc  = (const float*)d_in[11];
    float* out = (float*)d_out;

    float* ws     = (float*)d_ws;
    float* energy = ws;             // 32*768        = 24576
    float* gw     = ws + 24576;     // 32*384        = 12288
    float* mu     = ws + 36864;     // 32*1024       = 32768
    float* rr     = ws + 69632;     // 32*1024       = 32768
    float* Spart  = ws + 102400;    // 32*32*384     = 393216
    float* ga     = ws + 495616;    // 32*384        = 12288

    k1_energy<<<6144, 64, 0, stream>>>(x, energy);
    k34_stats_S<<<1024, 384, 0, stream>>>(x, energy, w1, b1, w2, b2, alp, gw, mu, rr, Spart);
    k5_attn<<<32, 384, 0, stream>>>(Spart, mu, rr, lng, lnb, wg, bg, wc, bc, gw, ga);
    k6_out<<<3072, 256, 0, stream>>>(x, ga, out);
}

// Round 11
// 94.679 us; speedup vs baseline: 2.3947x; 1.0312x over previous
//
#include <hip/hip_runtime.h>
#include <hip/hip_bf16.h>
#include <math.h>

#define EPSF 1e-8f
// dims: B=32, C=384, H=W=32, L=1024, RF=24, RA=48

__device__ __forceinline__ float gelu_exact(float z) {
    return 0.5f * z * (1.0f + erff(z * 0.70710678118654752440f));
}
__device__ __forceinline__ float sigmoidf(float z) {
    return 1.0f / (1.0f + expf(-z));
}

// bf16 pack/unpack (no cvt_pk builtin on gfx950 -> inline asm)
__device__ __forceinline__ unsigned pk_bf16(float lo, float hi) {
    unsigned r;
    asm("v_cvt_pk_bf16_f32 %0, %1, %2" : "=v"(r) : "v"(lo), "v"(hi));
    return r;
}
__device__ __forceinline__ float ubf_lo(unsigned u) { return __uint_as_float(u << 16); }
__device__ __forceinline__ float ubf_hi(unsigned u) { return __uint_as_float(u & 0xFFFF0000u); }

// ---------- compile-time twiddles: cos/sin(2*pi*k/32) ----------
constexpr float cqv(int i) {
    return i == 0 ? 1.0f : i == 1 ? 0.980785280403230449f : i == 2 ? 0.923879532511286756f
         : i == 3 ? 0.831469612302545237f : i == 4 ? 0.707106781186547524f
         : i == 5 ? 0.555570233019602225f : i == 6 ? 0.382683432365089772f
         : i == 7 ? 0.195090322016128268f : 0.0f;  // i==8 -> 0
}
constexpr float c32f(int k) {
    k = ((k % 32) + 32) % 32;
    int kk = (k > 16) ? 32 - k : k;
    return (kk <= 8) ? cqv(kk) : -cqv(16 - kk);
}
constexpr float s32f(int k) { return c32f(k - 8); }

// acc += w32^TI * (br + i*bi), optionally conjugating (br,bi). All literal.
template<int TI, bool CJ>
__device__ __forceinline__ void cmadd(float br, float bi, float& re, float& im) {
    constexpr float c0 = c32f(TI), s0 = s32f(TI);
    constexpr float sE = CJ ? -s0 : s0;
    constexpr float cE = CJ ? -c0 : c0;
    if constexpr (c0 != 0.f) re = fmaf(br, c0, re);
    if constexpr (s0 != 0.f) re = fmaf(bi, sE, re);
    if constexpr (c0 != 0.f) im = fmaf(bi, cE, im);
    if constexpr (s0 != 0.f) im = fmaf(br, -s0, im);
}

// ---------- stage 1: real 8-sample sub-DFTs (k mod 4 residues), base w8=w32^4 ----------
template<int RR, int N, int P>
struct G8 {
    static __device__ __forceinline__ void run(const float (&r)[32], float& re, float& im) {
        constexpr int ti = (4 * N * P) % 32;
        constexpr float c = c32f(ti), s = s32f(ti);
        if constexpr (c != 0.f) re = fmaf(r[4*P+RR], c, re);
        if constexpr (s != 0.f) im = fmaf(r[4*P+RR], -s, im);
        if constexpr (P + 1 < 8) G8<RR, N, P+1>::run(r, re, im);
    }
};
template<int RR, int N>
struct G8N {
    static __device__ __forceinline__ void run(const float (&r)[32], float (&Gre)[4][5], float (&Gim)[4][5]) {
        float re = 0.f, im = 0.f;
        G8<RR, N, 0>::run(r, re, im);
        Gre[RR][N] = re; Gim[RR][N] = im;
        if constexpr (N + 1 < 5) G8N<RR, N+1>::run(r, Gre, Gim);
    }
};
template<int RR>
struct G8R {
    static __device__ __forceinline__ void run(const float (&r)[32], float (&Gre)[4][5], float (&Gim)[4][5]) {
        G8N<RR, 0>::run(r, Gre, Gim);
        if constexpr (RR + 1 < 4) G8R<RR+1>::run(r, Gre, Gim);
    }
};
// stage-1 combine: R[v] = sum_r w32^{v r} G_r[v mod 8], conj-fetch for n>4 (real symmetry)
template<int V>
struct S1C {
    static __device__ __forceinline__ void run(const float (&Gre)[4][5], const float (&Gim)[4][5],
                                               unsigned* Rp, int base) {
        constexpr int n = V & 7;
        constexpr int nn = (n <= 4) ? n : 8 - n;
        constexpr bool cj = (n > 4);
        float re = 0.f, im = 0.f;
        cmadd<0,   cj>(Gre[0][nn], Gim[0][nn], re, im);
        cmadd<V,   cj>(Gre[1][nn], Gim[1][nn], re, im);
        cmadd<2*V, cj>(Gre[2][nn], Gim[2][nn], re, im);
        cmadd<3*V, cj>(Gre[3][nn], Gim[3][nn], re, im);
        Rp[base + V * 33] = pk_bf16(re, im);
        if constexpr (V + 1 < 17) S1C<V+1>::run(Gre, Gim, Rp, base);
    }
};

// ---------- stage 2 high: complex 4-sample sub-DFTs (k mod 4), base w8 ----------
template<int RR, int N, int P>
struct D4 {
    static __device__ __forceinline__ void run(const float (&dr)[16], const float (&di)[16],
                                               float& re, float& im) {
        cmadd<(4*N*P) % 32, false>(dr[4*P+RR], di[4*P+RR], re, im);
        if constexpr (P + 1 < 4) D4<RR, N, P+1>::run(dr, di, re, im);
    }
};
template<int RR, int N>
struct D4N {
    static __device__ __forceinline__ void run(const float (&dr)[16], const float (&di)[16],
                                               float (&Dre)[4][8], float (&Dim)[4][8]) {
        float re = 0.f, im = 0.f;
        D4<RR, N, 0>::run(dr, di, re, im);
        Dre[RR][N] = re; Dim[RR][N] = im;
        if constexpr (N + 1 < 8) D4N<RR, N+1>::run(dr, di, Dre, Dim);
    }
};
template<int RR>
struct D4R {
    static __device__ __forceinline__ void run(const float (&dr)[16], const float (&di)[16],
                                               float (&Dre)[4][8], float (&Dim)[4][8]) {
        D4N<RR, 0>::run(dr, di, Dre, Dim);
        if constexpr (RR + 1 < 4) D4R<RR+1>::run(dr, di, Dre, Dim);
    }
};
// stage-2 combine+mag: P[u] = sum_r w32^{u r} D_r[u mod 8]; half-split sign fix + pair shfl
template<int U>
struct S2C {
    static __device__ __forceinline__ void run(const float (&Dre)[4][8], const float (&Dim)[4][8],
                                               float sgn, float& acc) {
        constexpr int n = U & 7;
        float re = 0.f, im = 0.f;
        cmadd<0,   false>(Dre[0][n], Dim[0][n], re, im);
        cmadd<U,   false>(Dre[1][n], Dim[1][n], re, im);
        cmadd<2*U, false>(Dre[2][n], Dim[2][n], re, im);
        cmadd<3*U, false>(Dre[3][n], Dim[3][n], re, im);
        if constexpr (U & 1) { re *= sgn; im *= sgn; }
        float tr = re + __shfl_xor(re, 1);
        float ti = im + __shfl_xor(im, 1);
        acc += sqrtf(fmaf(tr, tr, ti * ti));
        if constexpr (U + 1 < 32) S2C<U+1>::run(Dre, Dim, sgn, acc);
    }
};

// ---------- low bins: 4-sample partial + runtime rotation + 8-lane reduce ----------
template<int U, int H, int HEND, int N>
struct S2T {
    static __device__ __forceinline__ void run(const float (&ar)[N], const float (&ai)[N],
                                               float& re, float& im) {
        constexpr float c = c32f(U * H);
        constexpr float s = s32f(U * H);
        if constexpr (c != 0.0f) { re = fmaf(ar[H], c, re); im = fmaf(ai[H], c, im); }
        if constexpr (s != 0.0f) { re = fmaf(ai[H], s, re); im = fmaf(ar[H], -s, im); }
        if constexpr (H + 1 < HEND) S2T<U, H + 1, HEND, N>::run(ar, ai, re, im);
    }
};
template<int U>
struct LowU {
    static __device__ __forceinline__ void run(const float (&er)[4], const float (&ei)[4],
                                               float wre, float wim, float brc, float brs,
                                               float& acc) {
        float pr = 0.f, pi = 0.f;
        S2T<U, 0, 4, 4>::run(er, ei, pr, pi);
        float vr = pr * wre - pi * wim;
        float vi = pr * wim + pi * wre;
        vr += __shfl_xor(vr, 1); vi += __shfl_xor(vi, 1);
        vr += __shfl_xor(vr, 2); vi += __shfl_xor(vi, 2);
        vr += __shfl_xor(vr, 4); vi += __shfl_xor(vi, 4);
        acc += sqrtf(fmaf(vr, vr, vi * vi));
        if constexpr (U + 1 < 8) {
            float nre = fmaf(wre, brc, -wim * brs);
            float nim = fmaf(wre, brs, wim * brc);
            LowU<U + 1>::run(er, ei, nre, nim, brc, brs, acc);
        }
    }
};

// ---------------- K1: per-image rfft2 magnitudes -> energy[b, 2C] ----------------
// 2 images/wave, grid 6144. Radix-4 two-level DFT, literal twiddles throughout.
__global__ void __launch_bounds__(64) k1_energy(const float* __restrict__ x,
                                                float* __restrict__ energy) {
    __shared__ __align__(16) unsigned Rp[2 * 561];
    const int t = threadIdx.x;
    const int img = t >> 5, h = t & 31;
    const int bc0 = blockIdx.x * 2;
    const float4* src = (const float4*)(x + (size_t)(bc0 + img) * 1024 + h * 32);
    float r[32];
#pragma unroll
    for (int k = 0; k < 8; ++k) {
        float4 a = src[k];
        r[4*k+0] = a.x; r[4*k+1] = a.y; r[4*k+2] = a.z; r[4*k+3] = a.w;
    }
    {
        float Gre[4][5], Gim[4][5];
        G8R<0>::run(r, Gre, Gim);
        S1C<0>::run(Gre, Gim, Rp, img * 561 + h);
    }
    __syncthreads();

    const int q = t & 31;
    // ---- high phase: 13 columns (v=4..16) x 2 h-halves = 26 tasks/img ----
    float acch = 0.f;
    {
        const int vq = (q < 26) ? (4 + (q >> 1)) : 4;
        const int h0 = (q < 26) ? ((q & 1) << 4) : 0;
        const unsigned* bp = &Rp[img * 561 + vq * 33 + h0];
        float dr[16], di[16];
#pragma unroll
        for (int k = 0; k < 16; ++k) { unsigned u = bp[k]; dr[k] = ubf_lo(u); di[k] = ubf_hi(u); }
        const float sgn = (h0 != 0) ? -1.0f : 1.0f;
        float Dre[4][8], Dim[4][8];
        D4R<0>::run(dr, di, Dre, Dim);
        S2C<8>::run(Dre, Dim, sgn, acch);
    }
    // ---- low phase: 4 columns (v=0..3) x 8 h-eighths = 32 tasks/img ----
    float accl = 0.f;
    {
        const int v2 = q >> 3, k8 = q & 7;
        const unsigned* lp = &Rp[img * 561 + v2 * 33 + k8 * 4];
        float er[4], ei[4];
#pragma unroll
        for (int j = 0; j < 4; ++j) { unsigned u = lp[j]; er[j] = ubf_lo(u); ei[j] = ubf_hi(u); }
        float sb, cb;
        sincosf(0.78539816339744831f * (float)k8, &sb, &cb);
        LowU<0>::run(er, ei, 1.0f, 0.0f, cb, -sb, accl);
    }
    float hv = (q < 26) ? acch : 0.f;
#pragma unroll
    for (int off = 1; off <= 16; off <<= 1) {
        hv   += __shfl_xor(hv, off);
        accl += __shfl_xor(accl, off);
    }
    if (q == 0) {
        const int bc = bc0 + img;
        const int b = bc / 384, c = bc - 384 * b;
        energy[b * 768 + c]       = accl * (1.0f / 8192.0f)  + EPSF;  // /(8 dup * 32 bins * 32 norm)
        energy[b * 768 + 384 + c] = hv   * (1.0f / 19968.0f) + EPSF;  // /(2 dup * 312 bins * 32 norm)
    }
}

// ---------------- K34: gw (fused k2) + LN stats + partial S ----------------
// Block = (b, l-slice of 32), 384 threads. Thread t <-> (c0=t>>3, j=t&7) owns
// rows c = c0+48i (i<8) at float4-column j: wave-load = 8 FULL 128B lines, and
// the 8 float4s stay in REGISTERS for phase B (x read exactly once; R10's
// 64-line/instr gather deleted). LDS pads: [32][49] (17t%32 distinct),
// [384][9] (9 coprime 32) -> all accesses <=2-way (free).
__global__ void __launch_bounds__(384) k34_stats_S(const float* __restrict__ x,
                                                   const float* __restrict__ energy,
                                                   const float* __restrict__ w1,
                                                   const float* __restrict__ b1,
                                                   const float* __restrict__ w2,
                                                   const float* __restrict__ b2,
                                                   const float* __restrict__ alp,
                                                   float* __restrict__ gw,
                                                   float* __restrict__ mu,
                                                   float* __restrict__ rr,
                                                   float* __restrict__ Spart) {
    const int b = blockIdx.x >> 5, sl = blockIdx.x & 31;
    const int t = threadIdx.x;
    __shared__ float e[768];
    __shared__ float hid24[24];
    __shared__ float gw_sh[384];
    __shared__ float ps[32][49], pq[32][49];
    __shared__ __align__(16) float r_sh[32];
    __shared__ float spB[384][9];
    // ---- phase 0: gw = 1 + alpha*sigmoid(MLP(energy)) ----
    e[t] = energy[b * 768 + t];
    e[t + 384] = energy[b * 768 + 384 + t];
    __syncthreads();
    {
        const int jh = t >> 4, s = t & 15;   // 24 hidden x 16 slices of 48
        const int k0 = s * 48;
        float a0 = 0.f, a1 = 0.f;
#pragma unroll
        for (int k = 0; k < 48; k += 2) {
            a0 = fmaf(e[k0 + k],     w1[(k0 + k) * 24 + jh],     a0);
            a1 = fmaf(e[k0 + k + 1], w1[(k0 + k + 1) * 24 + jh], a1);
        }
        float a = a0 + a1;
        a += __shfl_xor(a, 1); a += __shfl_xor(a, 2);
        a += __shfl_xor(a, 4); a += __shfl_xor(a, 8);
        if (s == 0) hid24[jh] = gelu_exact(a + b1[jh]);
    }
    __syncthreads();
    {
        float z = b2[t];
#pragma unroll
        for (int jh = 0; jh < 24; ++jh) z = fmaf(hid24[jh], w2[jh * 384 + t], z);
        float g = fmaf(alp[0], sigmoidf(z), 1.0f);
        gw_sh[t] = g;
        if (sl == 0) gw[b * 384 + t] = g;    // publish for k5
    }
    __syncthreads();
    // ---- phase A: load x-slice into registers (coalesced) + LN partials ----
    const float* xb = x + (size_t)b * 393216 + sl * 32;
    const int c0 = t >> 3;   // 0..47
    const int j  = t & 7;    // float4 column within 32-l row
    float4 xs0, xs1, xs2, xs3, xs4, xs5, xs6, xs7;
    {
        const float* p = xb + (size_t)c0 * 1024 + j * 4;
        xs0 = *(const float4*)(p);
        xs1 = *(const float4*)(p +  48 * 1024);
        xs2 = *(const float4*)(p +  96 * 1024);
        xs3 = *(const float4*)(p + 144 * 1024);
        xs4 = *(const float4*)(p + 192 * 1024);
        xs5 = *(const float4*)(p + 240 * 1024);
        xs6 = *(const float4*)(p + 288 * 1024);
        xs7 = *(const float4*)(p + 336 * 1024);
    }
    {
        float s0 = 0.f, s1 = 0.f, s2 = 0.f, s3 = 0.f;
        float q0 = 0.f, q1 = 0.f, q2 = 0.f, q3 = 0.f;
#define ACC(XS, I) { const float w = gw_sh[c0 + 48*(I)]; \
        float f0 = w*(XS).x, f1 = w*(XS).y, f2 = w*(XS).z, f3 = w*(XS).w; \
        s0 += f0; s1 += f1; s2 += f2; s3 += f3; \
        q0 = fmaf(f0,f0,q0); q1 = fmaf(f1,f1,q1); q2 = fmaf(f2,f2,q2); q3 = fmaf(f3,f3,q3); }
        ACC(xs0,0) ACC(xs1,1) ACC(xs2,2) ACC(xs3,3)
        ACC(xs4,4) ACC(xs5,5) ACC(xs6,6) ACC(xs7,7)
#undef ACC
        ps[4*j+0][c0] = s0; ps[4*j+1][c0] = s1; ps[4*j+2][c0] = s2; ps[4*j+3][c0] = s3;
        pq[4*j+0][c0] = q0; pq[4*j+1][c0] = q1; pq[4*j+2][c0] = q2; pq[4*j+3][c0] = q3;
    }
    __syncthreads();
    if (t < 32) {
        float S = 0.f, Q = 0.f;
#pragma unroll
        for (int i = 0; i < 48; ++i) { S += ps[t][i]; Q += pq[t][i]; }
        float m = S * (1.0f / 384.0f);
        float var = Q * (1.0f / 384.0f) - m * m;
        float rv = rsqrtf(var + 1e-5f);
        mu[b * 1024 + sl * 32 + t] = m;
        rr[b * 1024 + sl * 32 + t] = rv;
        r_sh[t] = rv;
    }
    __syncthreads();
    // ---- phase B: Spart from registers (no reload) ----
    {
        const float4 r4 = *(const float4*)&r_sh[4 * j];
#define DOT(XS, I) { float d = (XS).x * r4.x; d = fmaf((XS).y, r4.y, d); \
        d = fmaf((XS).z, r4.z, d); d = fmaf((XS).w, r4.w, d); spB[c0 + 48*(I)][j] = d; }
        DOT(xs0,0) DOT(xs1,1) DOT(xs2,2) DOT(xs3,3)
        DOT(xs4,4) DOT(xs5,5) DOT(xs6,6) DOT(xs7,7)
#undef DOT
    }
    __syncthreads();
    {
        float acc = 0.f;
#pragma unroll
        for (int k = 0; k < 8; ++k) acc += spB[t][k];
        Spart[((size_t)b * 32 + sl) * 384 + t] = acc;   // raw (gw applied in k5)
    }
}

// ---------------- K5: ga[b,c] = 4*sigmoid(gelu(xg@wg+bg)@wc+bc) * gw, per b ----------------
__global__ void __launch_bounds__(384) k5_attn(const float* __restrict__ Spart,
                                               const float* __restrict__ mu,
                                               const float* __restrict__ rr,
                                               const float* __restrict__ g,
                                               const float* __restrict__ beta,
                                               const float* __restrict__ wg,
                                               const float* __restrict__ bg,
                                               const float* __restrict__ wc,
                                               const float* __restrict__ bc_,
                                               const float* __restrict__ gw,
                                               float* __restrict__ ga) {
    __shared__ float red[6];
    __shared__ float xg[384];
    __shared__ float hid[48];
    const int b = blockIdx.x, t = threadIdx.x;
    const int wv = t >> 6, lane = t & 63;
    float p = 0.0f;
    for (int l = t; l < 1024; l += 384) p += mu[b * 1024 + l] * rr[b * 1024 + l];
#pragma unroll
    for (int off = 32; off > 0; off >>= 1) p += __shfl_down(p, off, 64);
    if (lane == 0) red[wv] = p;
    float Sraw = 0.f;
    {
        const float* sp = Spart + (size_t)b * 12288 + t;
#pragma unroll 8
        for (int sl = 0; sl < 32; ++sl) Sraw += sp[sl * 384];
    }
    __syncthreads();
    float T = red[0] + red[1] + red[2] + red[3] + red[4] + red[5];
    float Sc = gw[b * 384 + t] * Sraw;
    xg[t] = fmaf(g[t], (Sc - T) * (1.0f / 1024.0f), 0.0f) + beta[t];
    __syncthreads();
    {
        const int j = t >> 3, s = t & 7;    // 48 hidden x 8 slices of 48
        float a0 = 0.f, a1 = 0.f;
        const int k0 = s * 48;
#pragma unroll
        for (int k = 0; k < 48; k += 2) {
            a0 = fmaf(xg[k0 + k],     wg[(k0 + k) * 48 + j],     a0);
            a1 = fmaf(xg[k0 + k + 1], wg[(k0 + k + 1) * 48 + j], a1);
        }
        float a = a0 + a1;
        a += __shfl_xor(a, 1); a += __shfl_xor(a, 2); a += __shfl_xor(a, 4);
        if (s == 0) hid[j] = gelu_exact(a + bg[j]);
    }
    __syncthreads();
    float z = bc_[t];
#pragma unroll
    for (int j = 0; j < 48; ++j) z = fmaf(hid[j], wc[j * 384 + t], z);
    ga[b * 384 + t] = 4.0f * sigmoidf(z) * gw[b * 384 + t];
}

// ---------------- K6: out[b,l,c] = x[b,c,l] * ga[b,c] (LDS transpose, float4 stores) ----------
__global__ void __launch_bounds__(256) k6_out(const float* __restrict__ x,
                                              const float* __restrict__ ga,
                                              float* __restrict__ out) {
    __shared__ float tile[64][65];
    const int id = blockIdx.x;
    const int b = id / 96, rem = id - 96 * b;
    const int lt = rem / 6, ct = rem - 6 * lt;
    const int t = threadIdx.x, w = t >> 6, lane = t & 63;
    const float* xb = x + ((size_t)b * 384 + ct * 64) * 1024 + lt * 64;
#pragma unroll
    for (int i = 0; i < 16; ++i) {
        int cc = w + 4 * i;
        float coeff = ga[b * 384 + ct * 64 + cc];
        tile[cc][lane] = coeff * xb[(size_t)cc * 1024 + lane];
    }
    __syncthreads();
    const int c4 = (t & 15) * 4;
    const int lb = t >> 4;
    float* ob = out + ((size_t)b * 1024 + lt * 64) * 384 + ct * 64;
#pragma unroll
    for (int rep = 0; rep < 4; ++rep) {
        int ll = rep * 16 + lb;
        float4 v;
        v.x = tile[c4 + 0][ll];
        v.y = tile[c4 + 1][ll];
        v.z = tile[c4 + 2][ll];
        v.w = tile[c4 + 3][ll];
        *(float4*)(ob + (size_t)ll * 384 + c4) = v;
    }
}

extern "C" void kernel_launch(void* const* d_in, const int* in_sizes, int n_in,
                              void* d_out, int out_size, void* d_ws, size_t ws_size,
                              hipStream_t stream) {
    const float* x   = (const float*)d_in[0];
    const float* w1  = (const float*)d_in[1];
    const float* b1  = (const float*)d_in[2];
    const float* w2  = (const float*)d_in[3];
    const float* b2  = (const float*)d_in[4];
    const float* alp = (const float*)d_in[5];
    const float* lng = (const float*)d_in[6];
    const float* lnb = (const float*)d_in[7];
    const float* wg  = (const float*)d_in[8];
    const float* bg  = (const float*)d_in[9];
    const float* wc  = (const float*)d_in[10];
    const float* bc  = (const float*)d_in[11];
    float* out = (float*)d_out;

    float* ws     = (float*)d_ws;
    float* energy = ws;             // 32*768        = 24576
    float* gw     = ws + 24576;     // 32*384        = 12288
    float* mu     = ws + 36864;     // 32*1024       = 32768
    float* rr     = ws + 69632;     // 32*1024       = 32768
    float* Spart  = ws + 102400;    // 32*32*384     = 393216
    float* ga     = ws + 495616;    // 32*384        = 12288

    k1_energy<<<6144, 64, 0, stream>>>(x, energy);
    k34_stats_S<<<1024, 384, 0, stream>>>(x, energy, w1, b1, w2, b2, alp, gw, mu, rr, Spart);
    k5_attn<<<32, 384, 0, stream>>>(Spart, mu, rr, lng, lnb, wg, bg, wc, bc, gw, ga);
    k6_out<<<3072, 256, 0, stream>>>(x, ga, out);
}

// Round 12
// 93.114 us; speedup vs baseline: 2.4350x; 1.0168x over previous
//
#include <hip/hip_runtime.h>
#include <hip/hip_bf16.h>
#include <math.h>

#define EPSF 1e-8f
// dims: B=32, C=384, H=W=32, L=1024, RF=24, RA=48

__device__ __forceinline__ float gelu_exact(float z) {
    return 0.5f * z * (1.0f + erff(z * 0.70710678118654752440f));
}
__device__ __forceinline__ float sigmoidf(float z) {
    return 1.0f / (1.0f + expf(-z));
}

// bf16 pack/unpack (no cvt_pk builtin on gfx950 -> inline asm)
__device__ __forceinline__ unsigned pk_bf16(float lo, float hi) {
    unsigned r;
    asm("v_cvt_pk_bf16_f32 %0, %1, %2" : "=v"(r) : "v"(lo), "v"(hi));
    return r;
}
__device__ __forceinline__ float ubf_lo(unsigned u) { return __uint_as_float(u << 16); }
__device__ __forceinline__ float ubf_hi(unsigned u) { return __uint_as_float(u & 0xFFFF0000u); }

// ---------- compile-time twiddles: cos/sin(2*pi*k/32) ----------
constexpr float cqv(int i) {
    return i == 0 ? 1.0f : i == 1 ? 0.980785280403230449f : i == 2 ? 0.923879532511286756f
         : i == 3 ? 0.831469612302545237f : i == 4 ? 0.707106781186547524f
         : i == 5 ? 0.555570233019602225f : i == 6 ? 0.382683432365089772f
         : i == 7 ? 0.195090322016128268f : 0.0f;  // i==8 -> 0
}
constexpr float c32f(int k) {
    k = ((k % 32) + 32) % 32;
    int kk = (k > 16) ? 32 - k : k;
    return (kk <= 8) ? cqv(kk) : -cqv(16 - kk);
}
constexpr float s32f(int k) { return c32f(k - 8); }

// acc += w32^TI * (br + i*bi), optionally conjugating (br,bi). All literal.
template<int TI, bool CJ>
__device__ __forceinline__ void cmadd(float br, float bi, float& re, float& im) {
    constexpr float c0 = c32f(TI), s0 = s32f(TI);
    constexpr float sE = CJ ? -s0 : s0;
    constexpr float cE = CJ ? -c0 : c0;
    if constexpr (c0 != 0.f) re = fmaf(br, c0, re);
    if constexpr (s0 != 0.f) re = fmaf(bi, sE, re);
    if constexpr (c0 != 0.f) im = fmaf(bi, cE, im);
    if constexpr (s0 != 0.f) im = fmaf(br, -s0, im);
}

// ---------- stage 1: real 8-sample sub-DFTs (k mod 4 residues), base w8=w32^4 ----------
template<int RR, int N, int P>
struct G8 {
    static __device__ __forceinline__ void run(const float (&r)[32], float& re, float& im) {
        constexpr int ti = (4 * N * P) % 32;
        constexpr float c = c32f(ti), s = s32f(ti);
        if constexpr (c != 0.f) re = fmaf(r[4*P+RR], c, re);
        if constexpr (s != 0.f) im = fmaf(r[4*P+RR], -s, im);
        if constexpr (P + 1 < 8) G8<RR, N, P+1>::run(r, re, im);
    }
};
template<int RR, int N>
struct G8N {
    static __device__ __forceinline__ void run(const float (&r)[32], float (&Gre)[4][5], float (&Gim)[4][5]) {
        float re = 0.f, im = 0.f;
        G8<RR, N, 0>::run(r, re, im);
        Gre[RR][N] = re; Gim[RR][N] = im;
        if constexpr (N + 1 < 5) G8N<RR, N+1>::run(r, Gre, Gim);
    }
};
template<int RR>
struct G8R {
    static __device__ __forceinline__ void run(const float (&r)[32], float (&Gre)[4][5], float (&Gim)[4][5]) {
        G8N<RR, 0>::run(r, Gre, Gim);
        if constexpr (RR + 1 < 4) G8R<RR+1>::run(r, Gre, Gim);
    }
};
// stage-1 combine: R[v] = sum_r w32^{v r} G_r[v mod 8], conj-fetch for n>4 (real symmetry)
template<int V>
struct S1C {
    static __device__ __forceinline__ void run(const float (&Gre)[4][5], const float (&Gim)[4][5],
                                               unsigned* Rp, int base) {
        constexpr int n = V & 7;
        constexpr int nn = (n <= 4) ? n : 8 - n;
        constexpr bool cj = (n > 4);
        float re = 0.f, im = 0.f;
        cmadd<0,   cj>(Gre[0][nn], Gim[0][nn], re, im);
        cmadd<V,   cj>(Gre[1][nn], Gim[1][nn], re, im);
        cmadd<2*V, cj>(Gre[2][nn], Gim[2][nn], re, im);
        cmadd<3*V, cj>(Gre[3][nn], Gim[3][nn], re, im);
        Rp[base + V * 33] = pk_bf16(re, im);
        if constexpr (V + 1 < 17) S1C<V+1>::run(Gre, Gim, Rp, base);
    }
};

// ---------- stage 2 high: complex 4-sample sub-DFTs (k mod 4), base w8 ----------
template<int RR, int N, int P>
struct D4 {
    static __device__ __forceinline__ void run(const float (&dr)[16], const float (&di)[16],
                                               float& re, float& im) {
        cmadd<(4*N*P) % 32, false>(dr[4*P+RR], di[4*P+RR], re, im);
        if constexpr (P + 1 < 4) D4<RR, N, P+1>::run(dr, di, re, im);
    }
};
template<int RR, int N>
struct D4N {
    static __device__ __forceinline__ void run(const float (&dr)[16], const float (&di)[16],
                                               float (&Dre)[4][8], float (&Dim)[4][8]) {
        float re = 0.f, im = 0.f;
        D4<RR, N, 0>::run(dr, di, re, im);
        Dre[RR][N] = re; Dim[RR][N] = im;
        if constexpr (N + 1 < 8) D4N<RR, N+1>::run(dr, di, Dre, Dim);
    }
};
template<int RR>
struct D4R {
    static __device__ __forceinline__ void run(const float (&dr)[16], const float (&di)[16],
                                               float (&Dre)[4][8], float (&Dim)[4][8]) {
        D4N<RR, 0>::run(dr, di, Dre, Dim);
        if constexpr (RR + 1 < 4) D4R<RR+1>::run(dr, di, Dre, Dim);
    }
};
// stage-2 combine+mag: P[u] = sum_r w32^{u r} D_r[u mod 8]; half-split sign fix + pair shfl
template<int U>
struct S2C {
    static __device__ __forceinline__ void run(const float (&Dre)[4][8], const float (&Dim)[4][8],
                                               float sgn, float& acc) {
        constexpr int n = U & 7;
        float re = 0.f, im = 0.f;
        cmadd<0,   false>(Dre[0][n], Dim[0][n], re, im);
        cmadd<U,   false>(Dre[1][n], Dim[1][n], re, im);
        cmadd<2*U, false>(Dre[2][n], Dim[2][n], re, im);
        cmadd<3*U, false>(Dre[3][n], Dim[3][n], re, im);
        if constexpr (U & 1) { re *= sgn; im *= sgn; }
        float tr = re + __shfl_xor(re, 1);
        float ti = im + __shfl_xor(im, 1);
        acc += sqrtf(fmaf(tr, tr, ti * ti));
        if constexpr (U + 1 < 32) S2C<U+1>::run(Dre, Dim, sgn, acc);
    }
};

// ---------- low bins: 4-sample partial + runtime rotation + 8-lane reduce ----------
template<int U, int H, int HEND, int N>
struct S2T {
    static __device__ __forceinline__ void run(const float (&ar)[N], const float (&ai)[N],
                                               float& re, float& im) {
        constexpr float c = c32f(U * H);
        constexpr float s = s32f(U * H);
        if constexpr (c != 0.0f) { re = fmaf(ar[H], c, re); im = fmaf(ai[H], c, im); }
        if constexpr (s != 0.0f) { re = fmaf(ai[H], s, re); im = fmaf(ar[H], -s, im); }
        if constexpr (H + 1 < HEND) S2T<U, H + 1, HEND, N>::run(ar, ai, re, im);
    }
};
template<int U>
struct LowU {
    static __device__ __forceinline__ void run(const float (&er)[4], const float (&ei)[4],
                                               float wre, float wim, float brc, float brs,
                                               float& acc) {
        float pr = 0.f, pi = 0.f;
        S2T<U, 0, 4, 4>::run(er, ei, pr, pi);
        float vr = pr * wre - pi * wim;
        float vi = pr * wim + pi * wre;
        vr += __shfl_xor(vr, 1); vi += __shfl_xor(vi, 1);
        vr += __shfl_xor(vr, 2); vi += __shfl_xor(vi, 2);
        vr += __shfl_xor(vr, 4); vi += __shfl_xor(vi, 4);
        acc += sqrtf(fmaf(vr, vr, vi * vi));
        if constexpr (U + 1 < 8) {
            float nre = fmaf(wre, brc, -wim * brs);
            float nim = fmaf(wre, brs, wim * brc);
            LowU<U + 1>::run(er, ei, nre, nim, brc, brs, acc);
        }
    }
};

// ---------------- K1: per-image rfft2 magnitudes -> energy[b, 2C] (frozen) ----------------
__global__ void __launch_bounds__(64) k1_energy(const float* __restrict__ x,
                                                float* __restrict__ energy) {
    __shared__ __align__(16) unsigned Rp[2 * 561];
    const int t = threadIdx.x;
    const int img = t >> 5, h = t & 31;
    const int bc0 = blockIdx.x * 2;
    const float4* src = (const float4*)(x + (size_t)(bc0 + img) * 1024 + h * 32);
    float r[32];
#pragma unroll
    for (int k = 0; k < 8; ++k) {
        float4 a = src[k];
        r[4*k+0] = a.x; r[4*k+1] = a.y; r[4*k+2] = a.z; r[4*k+3] = a.w;
    }
    {
        float Gre[4][5], Gim[4][5];
        G8R<0>::run(r, Gre, Gim);
        S1C<0>::run(Gre, Gim, Rp, img * 561 + h);
    }
    __syncthreads();

    const int q = t & 31;
    float acch = 0.f;
    {
        const int vq = (q < 26) ? (4 + (q >> 1)) : 4;
        const int h0 = (q < 26) ? ((q & 1) << 4) : 0;
        const unsigned* bp = &Rp[img * 561 + vq * 33 + h0];
        float dr[16], di[16];
#pragma unroll
        for (int k = 0; k < 16; ++k) { unsigned u = bp[k]; dr[k] = ubf_lo(u); di[k] = ubf_hi(u); }
        const float sgn = (h0 != 0) ? -1.0f : 1.0f;
        float Dre[4][8], Dim[4][8];
        D4R<0>::run(dr, di, Dre, Dim);
        S2C<8>::run(Dre, Dim, sgn, acch);
    }
    float accl = 0.f;
    {
        const int v2 = q >> 3, k8 = q & 7;
        const unsigned* lp = &Rp[img * 561 + v2 * 33 + k8 * 4];
        float er[4], ei[4];
#pragma unroll
        for (int j = 0; j < 4; ++j) { unsigned u = lp[j]; er[j] = ubf_lo(u); ei[j] = ubf_hi(u); }
        float sb, cb;
        sincosf(0.78539816339744831f * (float)k8, &sb, &cb);
        LowU<0>::run(er, ei, 1.0f, 0.0f, cb, -sb, accl);
    }
    float hv = (q < 26) ? acch : 0.f;
#pragma unroll
    for (int off = 1; off <= 16; off <<= 1) {
        hv   += __shfl_xor(hv, off);
        accl += __shfl_xor(accl, off);
    }
    if (q == 0) {
        const int bc = bc0 + img;
        const int b = bc / 384, c = bc - 384 * b;
        energy[b * 768 + c]       = accl * (1.0f / 8192.0f)  + EPSF;
        energy[b * 768 + 384 + c] = hv   * (1.0f / 19968.0f) + EPSF;
    }
}

// ---------------- K2: gw = 1 + alpha*sigmoid(gelu(energy@w1+b1)@w2+b2), per b ----------------
__global__ void __launch_bounds__(64) k2_mlp(const float* __restrict__ energy,
                                             const float* __restrict__ w1,
                                             const float* __restrict__ b1,
                                             const float* __restrict__ w2,
                                             const float* __restrict__ b2,
                                             const float* __restrict__ alp,
                                             float* __restrict__ gw) {
    __shared__ float e[768];
    __shared__ float hid[24];
    const int b = blockIdx.x, t = threadIdx.x;
    for (int i = t; i < 768; i += 64) e[i] = energy[b * 768 + i];
    __syncthreads();
    if (t < 24) {
        float a0 = 0.f, a1 = 0.f, a2 = 0.f, a3 = 0.f;
        for (int k = 0; k < 768; k += 4) {
            a0 = fmaf(e[k+0], w1[(k+0) * 24 + t], a0);
            a1 = fmaf(e[k+1], w1[(k+1) * 24 + t], a1);
            a2 = fmaf(e[k+2], w1[(k+2) * 24 + t], a2);
            a3 = fmaf(e[k+3], w1[(k+3) * 24 + t], a3);
        }
        hid[t] = gelu_exact(((a0 + a1) + (a2 + a3)) + b1[t]);
    }
    __syncthreads();
    const float alpha = alp[0];
    for (int c = t; c < 384; c += 64) {
        float z = b2[c];
#pragma unroll
        for (int j = 0; j < 24; ++j) z = fmaf(hid[j], w2[j * 384 + c], z);
        gw[b * 384 + c] = fmaf(alpha, sigmoidf(z), 1.0f);
    }
}

// ---------------- KA: LN partials, barrier-free streaming ----------------
// grid 1024 = (b, c-chunk of 12); 256 thr; thread t owns l = 4t..4t+3.
// Streams 12 full 4KB rows (float4 coalesced); writes per-chunk partials.
__global__ void __launch_bounds__(256) kA_partial(const float* __restrict__ x,
                                                  const float* __restrict__ gw,
                                                  float* __restrict__ part_s,
                                                  float* __restrict__ part_q) {
    const int b = blockIdx.x >> 5, ch = blockIdx.x & 31;
    const int t = threadIdx.x;
    const int cbase = ch * 12;
    float s0 = 0.f, s1 = 0.f, s2 = 0.f, s3 = 0.f;
    float q0 = 0.f, q1 = 0.f, q2 = 0.f, q3 = 0.f;
#pragma unroll
    for (int cc = 0; cc < 12; ++cc) {
        const int c = cbase + cc;
        float4 v = ((const float4*)(x + ((size_t)(b * 384 + c) << 10)))[t];
        const float w = gw[b * 384 + c];
        float f0 = w * v.x, f1 = w * v.y, f2 = w * v.z, f3 = w * v.w;
        s0 += f0; s1 += f1; s2 += f2; s3 += f3;
        q0 = fmaf(f0, f0, q0); q1 = fmaf(f1, f1, q1);
        q2 = fmaf(f2, f2, q2); q3 = fmaf(f3, f3, q3);
    }
    const size_t o = ((size_t)(b * 32 + ch) << 10);
    ((float4*)(part_s + o))[t] = make_float4(s0, s1, s2, s3);
    ((float4*)(part_q + o))[t] = make_float4(q0, q1, q2, q3);
}

// ---------------- KB: combine partials -> rr[b,l], Tpart[b][8] ----------------
// grid 256 = (b, l-chunk of 128); 128 thr; thread -> one l.
__global__ void __launch_bounds__(128) kB_stats(const float* __restrict__ part_s,
                                                const float* __restrict__ part_q,
                                                float* __restrict__ rr,
                                                float* __restrict__ Tpart) {
    const int b = blockIdx.x >> 3, lc = blockIdx.x & 7;
    const int t = threadIdx.x;
    const int l = lc * 128 + t;
    float S = 0.f, Q = 0.f;
#pragma unroll 8
    for (int ch = 0; ch < 32; ++ch) {
        const size_t o = ((size_t)(b * 32 + ch) << 10) + l;
        S += part_s[o];
        Q += part_q[o];
    }
    const float m = S * (1.0f / 384.0f);
    const float var = Q * (1.0f / 384.0f) - m * m;
    const float rv = rsqrtf(var + 1e-5f);
    rr[b * 1024 + l] = rv;
    float tp = m * rv;
    tp += __shfl_xor(tp, 1);  tp += __shfl_xor(tp, 2);
    tp += __shfl_xor(tp, 4);  tp += __shfl_xor(tp, 8);
    tp += __shfl_xor(tp, 16); tp += __shfl_xor(tp, 32);
    __shared__ float red[2];
    if ((t & 63) == 0) red[t >> 6] = tp;
    __syncthreads();
    if (t == 0) Tpart[b * 8 + lc] = red[0] + red[1];
}

// ---------------- KC: S[b,c] = gw * sum_l x*r, streaming + wave reduce ----------------
// grid 1024 = (b, c-chunk of 12), same tiling as KA (rows L3-hot).
__global__ void __launch_bounds__(256) kC_S(const float* __restrict__ x,
                                            const float* __restrict__ gw,
                                            const float* __restrict__ rr,
                                            float* __restrict__ Sarr) {
    const int b = blockIdx.x >> 5, ch = blockIdx.x & 31;
    const int t = threadIdx.x;
    const int cbase = ch * 12;
    const float4 rv = ((const float4*)(rr + b * 1024))[t];
    __shared__ float part[12][5];
#pragma unroll
    for (int cc = 0; cc < 12; ++cc) {
        const int c = cbase + cc;
        float4 v = ((const float4*)(x + ((size_t)(b * 384 + c) << 10)))[t];
        float d = v.x * rv.x;
        d = fmaf(v.y, rv.y, d);
        d = fmaf(v.z, rv.z, d);
        d = fmaf(v.w, rv.w, d);
        d += __shfl_xor(d, 1);  d += __shfl_xor(d, 2);
        d += __shfl_xor(d, 4);  d += __shfl_xor(d, 8);
        d += __shfl_xor(d, 16); d += __shfl_xor(d, 32);
        if ((t & 63) == 0) part[cc][t >> 6] = d;
    }
    __syncthreads();
    if (t < 12) {
        const int c = cbase + t;
        Sarr[b * 384 + c] = gw[b * 384 + c] *
            (part[t][0] + part[t][1] + part[t][2] + part[t][3]);
    }
}

// ---------------- K5: ga[b,c] = 4*sigmoid(gelu(xg@wg+bg)@wc+bc) * gw, per b ----------------
__global__ void __launch_bounds__(384) k5_attn(const float* __restrict__ Sarr,
                                               const float* __restrict__ Tpart,
                                               const float* __restrict__ g,
                                               const float* __restrict__ beta,
                                               const float* __restrict__ wg,
                                               const float* __restrict__ bg,
                                               const float* __restrict__ wc,
                                               const float* __restrict__ bc_,
                                               const float* __restrict__ gw,
                                               float* __restrict__ ga) {
    __shared__ float xg[384];
    __shared__ float hid[48];
    const int b = blockIdx.x, t = threadIdx.x;
    float T = 0.f;
#pragma unroll
    for (int i = 0; i < 8; ++i) T += Tpart[b * 8 + i];
    xg[t] = fmaf(g[t], (Sarr[b * 384 + t] - T) * (1.0f / 1024.0f), 0.0f) + beta[t];
    __syncthreads();
    {
        const int j = t >> 3, s = t & 7;    // 48 hidden x 8 slices of 48
        float a0 = 0.f, a1 = 0.f;
        const int k0 = s * 48;
#pragma unroll
        for (int k = 0; k < 48; k += 2) {
            a0 = fmaf(xg[k0 + k],     wg[(k0 + k) * 48 + j],     a0);
            a1 = fmaf(xg[k0 + k + 1], wg[(k0 + k + 1) * 48 + j], a1);
        }
        float a = a0 + a1;
        a += __shfl_xor(a, 1); a += __shfl_xor(a, 2); a += __shfl_xor(a, 4);
        if (s == 0) hid[j] = gelu_exact(a + bg[j]);
    }
    __syncthreads();
    float z = bc_[t];
#pragma unroll
    for (int j = 0; j < 48; ++j) z = fmaf(hid[j], wc[j * 384 + t], z);
    ga[b * 384 + t] = 4.0f * sigmoidf(z) * gw[b * 384 + t];
}

// ---------------- K6: out[b,l,c] = x[b,c,l] * ga[b,c] (LDS transpose, float4 stores) ----------
__global__ void __launch_bounds__(256) k6_out(const float* __restrict__ x,
                                              const float* __restrict__ ga,
                                              float* __restrict__ out) {
    __shared__ float tile[64][65];
    const int id = blockIdx.x;
    const int b = id / 96, rem = id - 96 * b;
    const int lt = rem / 6, ct = rem - 6 * lt;
    const int t = threadIdx.x, w = t >> 6, lane = t & 63;
    const float* xb = x + ((size_t)b * 384 + ct * 64) * 1024 + lt * 64;
#pragma unroll
    for (int i = 0; i < 16; ++i) {
        int cc = w + 4 * i;
        float coeff = ga[b * 384 + ct * 64 + cc];
        tile[cc][lane] = coeff * xb[(size_t)cc * 1024 + lane];
    }
    __syncthreads();
    const int c4 = (t & 15) * 4;
    const int lb = t >> 4;
    float* ob = out + ((size_t)b * 1024 + lt * 64) * 384 + ct * 64;
#pragma unroll
    for (int rep = 0; rep < 4; ++rep) {
        int ll = rep * 16 + lb;
        float4 v;
        v.x = tile[c4 + 0][ll];
        v.y = tile[c4 + 1][ll];
        v.z = tile[c4 + 2][ll];
        v.w = tile[c4 + 3][ll];
        *(float4*)(ob + (size_t)ll * 384 + c4) = v;
    }
}

extern "C" void kernel_launch(void* const* d_in, const int* in_sizes, int n_in,
                              void* d_out, int out_size, void* d_ws, size_t ws_size,
                              hipStream_t stream) {
    const float* x   = (const float*)d_in[0];
    const float* w1  = (const float*)d_in[1];
    const float* b1  = (const float*)d_in[2];
    const float* w2  = (const float*)d_in[3];
    const float* b2  = (const float*)d_in[4];
    const float* alp = (const float*)d_in[5];
    const float* lng = (const float*)d_in[6];
    const float* lnb = (const float*)d_in[7];
    const float* wg  = (const float*)d_in[8];
    const float* bg  = (const float*)d_in[9];
    const float* wc  = (const float*)d_in[10];
    const float* bc  = (const float*)d_in[11];
    float* out = (float*)d_out;

    float* ws     = (float*)d_ws;
    float* energy = ws;               // 32*768       = 24576
    float* gw     = ws + 24576;       // 32*384       = 12288
    float* part_s = ws + 36864;       // 32*32*1024   = 1048576
    float* part_q = ws + 1085440;     // 1048576
    float* rr     = ws + 2134016;     // 32*1024      = 32768
    float* Tpart  = ws + 2166784;     // 32*8         = 256
    float* Sarr   = ws + 2167040;     // 32*384       = 12288
    float* ga     = ws + 2179328;     // 32*384       = 12288

    k1_energy<<<6144, 64, 0, stream>>>(x, energy);
    k2_mlp<<<32, 64, 0, stream>>>(energy, w1, b1, w2, b2, alp, gw);
    kA_partial<<<1024, 256, 0, stream>>>(x, gw, part_s, part_q);
    kB_stats<<<256, 128, 0, stream>>>(part_s, part_q, rr, Tpart);
    kC_S<<<1024, 256, 0, stream>>>(x, gw, rr, Sarr);
    k5_attn<<<32, 384, 0, stream>>>(Sarr, Tpart, lng, lnb, wg, bg, wc, bc, gw, ga);
    k6_out<<<3072, 256, 0, stream>>>(x, ga, out);
}